// Round 6
// baseline (176.457 us; speedup 1.0000x reference)
//
#include <hip/hip_runtime.h>

#define B_SZ  2
#define N_PTS 16384
#define M_CTR 4096
#define C_FT  32
#define K_NB  32
#define NCH   35   // 3 + C_FT

// ---------------------------------------------------------------------------
// Exact single-rounded f32 ops, opaque to the compiler (no re-association,
// no contraction). v_fma_f32 used ONLY where the numpy golden fuses.
// ---------------------------------------------------------------------------
__device__ __forceinline__ float fmul(float a, float b) {
    float r; asm("v_mul_f32 %0, %1, %2" : "=v"(r) : "v"(a), "v"(b)); return r;
}
__device__ __forceinline__ float fadd(float a, float b) {
    float r; asm("v_add_f32 %0, %1, %2" : "=v"(r) : "v"(a), "v"(b)); return r;
}
__device__ __forceinline__ float fsub(float a, float b) {
    float r; asm("v_sub_f32 %0, %1, %2" : "=v"(r) : "v"(a), "v"(b)); return r;
}
__device__ __forceinline__ float ffma(float a, float b, float c) {
    float r; asm("v_fma_f32 %0, %1, %2, %3" : "=v"(r) : "v"(a), "v"(b), "v"(c));
    return r;
}

// ---------------------------------------------------------------------------
// Kernel 1: ball query. One wave per center; first K valid indices in
// ascending order (reference's masked-arange + sort), early exit at K.
//
// dist2 mirrors the numpy golden's op-by-op rounding:
//   p2 = ((x*x) + (y*y)) + (z*z)     separate ufuncs: mul then np.sum -> no fma
//   c2 = ((cx*cx)+(cy*cy))+(cz*cz)   same
//   cp = fma(cz,z, fma(cy,y, cx*x))  einsum SOP loop / BLAS microkernel:
//                                    fma-contracted accumulation, k ascending
//   dist2 = (c2 + p2) - (2*cp)       binary ufuncs L2R; sub Sterbenz-exact
//   valid = dist2 < f32(0.1*0.1)
// Evidence: E1 (no-fma everywhere, R1==R5 -> 5.109375) and exact (R3==R4 ->
// 5.015625) are both a-few-flips off the golden; the fma-contracted cp is the
// unique remaining natural numpy evaluation (einsum and BLAS both yield it).
// ---------------------------------------------------------------------------
__global__ __launch_bounds__(256) void ball_query_kernel(
    const float* __restrict__ points,   // (B,3,N)
    const float* __restrict__ centers,  // (B,3,M)
    int* __restrict__ idx_out)          // (B,K,M)
{
    const int lane = threadIdx.x & 63;
    const int wid  = threadIdx.x >> 6;
    const int cid  = blockIdx.x * 4 + wid;   // global center id
    const int b = cid / M_CTR;
    const int m = cid - b * M_CTR;

    const float r2 = (float)(0.1 * 0.1);     // 0x3C23D70A

    const float cx = centers[(b * 3 + 0) * M_CTR + m];
    const float cy = centers[(b * 3 + 1) * M_CTR + m];
    const float cz = centers[(b * 3 + 2) * M_CTR + m];
    const float c2 = fadd(fadd(fmul(cx, cx), fmul(cy, cy)), fmul(cz, cz));

    const float* __restrict__ px = points + (b * 3 + 0) * N_PTS;
    const float* __restrict__ py = points + (b * 3 + 1) * N_PTS;
    const float* __restrict__ pz = points + (b * 3 + 2) * N_PTS;

    __shared__ int sidx[4][K_NB];

    int count = 0;  // wave-uniform running count of valid points seen
    for (int base = 0; base < N_PTS; base += 64) {
        const int n = base + lane;          // N divisible by 64, no tail
        const float x = px[n];
        const float y = py[n];
        const float z = pz[n];
        const float p2 = fadd(fadd(fmul(x, x), fmul(y, y)), fmul(z, z));
        const float cp = ffma(cz, z, ffma(cy, y, fmul(cx, x)));
        const float dist2 = fsub(fadd(c2, p2), fmul(2.0f, cp));
        const bool valid = dist2 < r2;
        const unsigned long long mask = __ballot(valid);
        if (valid) {
            const int pos = count + __popcll(mask & ((1ull << lane) - 1ull));
            if (pos < K_NB) sidx[wid][pos] = n;
        }
        count += (int)__popcll(mask);
        if (count >= K_NB) break;           // wave-uniform break
    }

    __syncthreads();  // all 4 waves reach this (break is wave-uniform)

    if (lane < K_NB) {
        int v;
        if (count == 0) {
            v = 0;                           // no valid neighbor -> index 0
        } else if (lane < count) {
            v = sidx[wid][lane];
        } else {
            v = sidx[wid][0];                // pad with first valid index
        }
        idx_out[(b * K_NB + lane) * M_CTR + m] = v;
    }
}

// ---------------------------------------------------------------------------
// Kernel 2: gather + concat + transpose. One thread per output element,
// linear index == output index (B,35,K,M), m fastest -> coalesced stores and
// coalesced idx reads. Feature channels are exact f32 pass-through; coord
// channel is a single f32 subtract (single-rounded, same as numpy).
// ---------------------------------------------------------------------------
__global__ __launch_bounds__(256) void gather_kernel(
    const float* __restrict__ points,   // (B,3,N)
    const float* __restrict__ centers,  // (B,3,M)
    const float* __restrict__ feats,    // (B,C,N)
    const int* __restrict__ idx,        // (B,K,M)
    float* __restrict__ out)            // (B,35,K,M)
{
    const int t = blockIdx.x * 256 + threadIdx.x;
    const int m = t & (M_CTR - 1);
    int r = t >> 12;                     // /4096
    const int k = r & (K_NB - 1);
    r >>= 5;
    const int ch = r % NCH;
    const int b  = r / NCH;

    const int n = idx[(b * K_NB + k) * M_CTR + m];

    float v;
    if (ch < 3) {
        v = points[(b * 3 + ch) * N_PTS + n]
          - centers[(b * 3 + ch) * M_CTR + m];
    } else {
        v = feats[(b * C_FT + (ch - 3)) * N_PTS + n];
    }
    out[t] = v;
}

extern "C" void kernel_launch(void* const* d_in, const int* in_sizes, int n_in,
                              void* d_out, int out_size, void* d_ws, size_t ws_size,
                              hipStream_t stream) {
    const float* points  = (const float*)d_in[0];  // (2,3,16384)
    const float* centers = (const float*)d_in[1];  // (2,3,4096)
    const float* feats   = (const float*)d_in[2];  // (2,32,16384)
    float* out = (float*)d_out;                    // (2,35,32,4096)
    int* idx = (int*)d_ws;                         // (2,32,4096) = 1 MiB

    ball_query_kernel<<<(B_SZ * M_CTR) / 4, 256, 0, stream>>>(
        points, centers, idx);

    const int total = B_SZ * NCH * K_NB * M_CTR;   // 9,175,040
    gather_kernel<<<total / 256, 256, 0, stream>>>(
        points, centers, feats, idx, out);
}

// Round 7
// 132.228 us; speedup vs baseline: 1.3345x; 1.3345x over previous
//
#include <hip/hip_runtime.h>

#define B_SZ  2
#define N_PTS 16384
#define M_CTR 4096
#define C_FT  32
#define K_NB  32
#define NCH   35   // 3 + C_FT
#define CH_STRIDE (K_NB * M_CTR)   // 131072

// ---------------------------------------------------------------------------
// Exact single-rounded f32 ops, opaque to the compiler. v_fma_f32 used ONLY
// where the numpy golden fuses (the einsum cp accumulation). This exact
// formula passed with absmax == 0.0 in R6 — DO NOT change the math.
// ---------------------------------------------------------------------------
__device__ __forceinline__ float fmul(float a, float b) {
    float r; asm("v_mul_f32 %0, %1, %2" : "=v"(r) : "v"(a), "v"(b)); return r;
}
__device__ __forceinline__ float fadd(float a, float b) {
    float r; asm("v_add_f32 %0, %1, %2" : "=v"(r) : "v"(a), "v"(b)); return r;
}
__device__ __forceinline__ float fsub(float a, float b) {
    float r; asm("v_sub_f32 %0, %1, %2" : "=v"(r) : "v"(a), "v"(b)); return r;
}
__device__ __forceinline__ float ffma(float a, float b, float c) {
    float r; asm("v_fma_f32 %0, %1, %2, %3" : "=v"(r) : "v"(a), "v"(b), "v"(c));
    return r;
}

__device__ __forceinline__ bool bq_valid(float x, float y, float z,
                                         float cx, float cy, float cz,
                                         float c2, float r2) {
    const float p2 = fadd(fadd(fmul(x, x), fmul(y, y)), fmul(z, z));
    const float cp = ffma(cz, z, ffma(cy, y, fmul(cx, x)));
    return fsub(fadd(c2, p2), fmul(2.0f, cp)) < r2;
}

// ---------------------------------------------------------------------------
// Kernel 1: ball query. One wave per center. R6 profile: VALUBusy 26%,
// HBM 0.4% -> latency-bound (~220 cyc per 64-pt iteration = one L2 hit).
// Fix: 4 points/lane via float4 (256 pts/chunk), next-chunk prefetch to
// overlap the load latency with the distance math, 4x fewer loop-carried
// latency exposures. Ordered compaction via 4 ballots (n = base+4*lane+j is
// lane-major, so lanes-below count + own-lower-j count gives the position).
// ---------------------------------------------------------------------------
__global__ __launch_bounds__(256) void ball_query_kernel(
    const float* __restrict__ points,   // (B,3,N)
    const float* __restrict__ centers,  // (B,3,M)
    int* __restrict__ idx_out)          // (B,K,M)
{
    const int lane = threadIdx.x & 63;
    const int wid  = threadIdx.x >> 6;
    const int cid  = blockIdx.x * 4 + wid;
    const int b = cid >> 12;            // / M_CTR
    const int m = cid & (M_CTR - 1);

    const float r2 = (float)(0.1 * 0.1);     // 0x3C23D70A

    const float cx = centers[(b * 3 + 0) * M_CTR + m];
    const float cy = centers[(b * 3 + 1) * M_CTR + m];
    const float cz = centers[(b * 3 + 2) * M_CTR + m];
    const float c2 = fadd(fadd(fmul(cx, cx), fmul(cy, cy)), fmul(cz, cz));

    const float4* __restrict__ px4 = (const float4*)(points + (b * 3 + 0) * N_PTS);
    const float4* __restrict__ py4 = (const float4*)(points + (b * 3 + 1) * N_PTS);
    const float4* __restrict__ pz4 = (const float4*)(points + (b * 3 + 2) * N_PTS);

    __shared__ int sidx[4][K_NB];

    const unsigned long long below = (1ull << lane) - 1ull;
    const int NCHUNK = N_PTS / 256;     // 64

    float4 X = px4[lane], Y = py4[lane], Z = pz4[lane];
    int count = 0;
    for (int chunk = 0; chunk < NCHUNK; ++chunk) {
        // prefetch next chunk (clamped redundant load on the last one)
        const int nc = (chunk + 1 < NCHUNK) ? chunk + 1 : chunk;
        const float4 Xn = px4[nc * 64 + lane];
        const float4 Yn = py4[nc * 64 + lane];
        const float4 Zn = pz4[nc * 64 + lane];

        const bool v0 = bq_valid(X.x, Y.x, Z.x, cx, cy, cz, c2, r2);
        const bool v1 = bq_valid(X.y, Y.y, Z.y, cx, cy, cz, c2, r2);
        const bool v2 = bq_valid(X.z, Y.z, Z.z, cx, cy, cz, c2, r2);
        const bool v3 = bq_valid(X.w, Y.w, Z.w, cx, cy, cz, c2, r2);

        const unsigned long long b0 = __ballot(v0);
        const unsigned long long b1 = __ballot(v1);
        const unsigned long long b2 = __ballot(v2);
        const unsigned long long b3 = __ballot(v3);

        int lp = count
               + (int)__popcll(b0 & below) + (int)__popcll(b1 & below)
               + (int)__popcll(b2 & below) + (int)__popcll(b3 & below);
        const int bn = chunk * 256 + 4 * lane;
        if (v0) { if (lp < K_NB) sidx[wid][lp] = bn + 0; ++lp; }
        if (v1) { if (lp < K_NB) sidx[wid][lp] = bn + 1; ++lp; }
        if (v2) { if (lp < K_NB) sidx[wid][lp] = bn + 2; ++lp; }
        if (v3) { if (lp < K_NB) sidx[wid][lp] = bn + 3; ++lp; }

        count += (int)__popcll(b0) + (int)__popcll(b1)
               + (int)__popcll(b2) + (int)__popcll(b3);
        if (count >= K_NB) break;       // wave-uniform
        X = Xn; Y = Yn; Z = Zn;
    }

    __syncthreads();

    if (lane < K_NB) {
        int v;
        if (count == 0)          v = 0;
        else if (lane < count)   v = sidx[wid][lane];
        else                     v = sidx[wid][0];
        idx_out[(b * K_NB + lane) * M_CTR + m] = v;
    }
}

// ---------------------------------------------------------------------------
// Kernel T: transpose points+feats (B,3,N)+(B,C,N) -> pf (B,N,36) so the
// gather reads each point's 35 channels as 9 contiguous float4s (full cache-
// line utilization) instead of 35 scattered 4B reads 64KB apart.
// ---------------------------------------------------------------------------
__global__ __launch_bounds__(256) void transpose_kernel(
    const float* __restrict__ points,   // (B,3,N)
    const float* __restrict__ feats,    // (B,C,N)
    float* __restrict__ pf)             // (B,N,36)
{
    __shared__ float tile[64][37];      // +1 pad vs bank conflicts
    const int t  = threadIdx.x;
    const int b  = blockIdx.x >> 8;
    const int n0 = (blockIdx.x & 255) * 64;

    for (int i = t; i < NCH * 64; i += 256) {
        const int r = i >> 6;           // channel 0..34
        const int c = i & 63;
        float v;
        if (r < 3) v = points[(b * 3 + r) * N_PTS + n0 + c];
        else       v = feats[(b * C_FT + (r - 3)) * N_PTS + n0 + c];
        tile[c][r] = v;
    }
    if (t < 64) tile[t][35] = 0.0f;     // pad channel
    __syncthreads();

    float* __restrict__ dst = pf + ((size_t)b * N_PTS + n0) * 36;
    for (int o = t; o < 64 * 36; o += 256) {
        const int c = o / 36;
        const int r = o - c * 36;
        dst[o] = tile[c][r];
    }
}

// ---------------------------------------------------------------------------
// Kernel 2: gather. One thread per (b,k,m): loads idx once, reads the point's
// 36-float record contiguously (9x dwordx4, L2-resident), writes 35 channel
// planes with m-fastest coalescing.
// ---------------------------------------------------------------------------
__global__ __launch_bounds__(256) void gather_kernel(
    const float* __restrict__ pf,       // (B,N,36)
    const float* __restrict__ centers,  // (B,3,M)
    const int* __restrict__ idx,        // (B,K,M)
    float* __restrict__ out)            // (B,35,K,M)
{
    const int t = blockIdx.x * 256 + threadIdx.x;   // 0..262143
    const int m = t & (M_CTR - 1);
    const int k = (t >> 12) & (K_NB - 1);
    const int b = t >> 17;

    const int n = idx[(b * K_NB + k) * M_CTR + m];
    const float4* __restrict__ src = (const float4*)(pf + ((size_t)b * N_PTS + n) * 36);

    float4 f[9];
#pragma unroll
    for (int i = 0; i < 9; ++i) f[i] = src[i];

    const float cx = centers[(b * 3 + 0) * M_CTR + m];
    const float cy = centers[(b * 3 + 1) * M_CTR + m];
    const float cz = centers[(b * 3 + 2) * M_CTR + m];

    float vv[36];
#pragma unroll
    for (int i = 0; i < 9; ++i) {
        vv[4 * i + 0] = f[i].x; vv[4 * i + 1] = f[i].y;
        vv[4 * i + 2] = f[i].z; vv[4 * i + 3] = f[i].w;
    }
    vv[0] -= cx; vv[1] -= cy; vv[2] -= cz;   // single f32 subtract, exact order

    float* __restrict__ o = out + ((size_t)b * NCH * K_NB + k) * M_CTR + m;
#pragma unroll
    for (int ch = 0; ch < NCH; ++ch)
        o[(size_t)ch * CH_STRIDE] = vv[ch];
}

extern "C" void kernel_launch(void* const* d_in, const int* in_sizes, int n_in,
                              void* d_out, int out_size, void* d_ws, size_t ws_size,
                              hipStream_t stream) {
    const float* points  = (const float*)d_in[0];  // (2,3,16384)
    const float* centers = (const float*)d_in[1];  // (2,3,4096)
    const float* feats   = (const float*)d_in[2];  // (2,32,16384)
    float* out = (float*)d_out;                    // (2,35,32,4096)

    int*   idx = (int*)d_ws;                                   // 1 MiB
    float* pf  = (float*)((char*)d_ws + (1u << 20));           // 4.5 MiB (B,N,36)

    ball_query_kernel<<<(B_SZ * M_CTR) / 4, 256, 0, stream>>>(points, centers, idx);
    transpose_kernel<<<B_SZ * (N_PTS / 64), 256, 0, stream>>>(points, feats, pf);

    const int total = B_SZ * K_NB * M_CTR;         // 262144
    gather_kernel<<<total / 256, 256, 0, stream>>>(pf, centers, idx, out);
}

// Round 8
// 114.549 us; speedup vs baseline: 1.5405x; 1.1543x over previous
//
#include <hip/hip_runtime.h>

#define B_SZ  2
#define N_PTS 16384
#define M_CTR 4096
#define C_FT  32
#define K_NB  32
#define NCH   35   // 3 + C_FT
#define CH_STRIDE (K_NB * M_CTR)   // 131072
#define CELLS 10                   // 10x10x10 grid, cell width 0.1 == radius
#define NCELL (CELLS * CELLS * CELLS)

// ---------------------------------------------------------------------------
// Exact single-rounded f32 ops, opaque to the compiler. v_fma_f32 ONLY where
// the numpy golden fuses (einsum cp accumulation). Passed absmax==0.0 in
// R6/R7 — DO NOT change the math.
// ---------------------------------------------------------------------------
__device__ __forceinline__ float fmul(float a, float b) {
    float r; asm("v_mul_f32 %0, %1, %2" : "=v"(r) : "v"(a), "v"(b)); return r;
}
__device__ __forceinline__ float fadd(float a, float b) {
    float r; asm("v_add_f32 %0, %1, %2" : "=v"(r) : "v"(a), "v"(b)); return r;
}
__device__ __forceinline__ float fsub(float a, float b) {
    float r; asm("v_sub_f32 %0, %1, %2" : "=v"(r) : "v"(a), "v"(b)); return r;
}
__device__ __forceinline__ float ffma(float a, float b, float c) {
    float r; asm("v_fma_f32 %0, %1, %2, %3" : "=v"(r) : "v"(a), "v"(b), "v"(c));
    return r;
}

__device__ __forceinline__ bool bq_valid(float x, float y, float z,
                                         float cx, float cy, float cz,
                                         float c2, float r2) {
    const float p2 = fadd(fadd(fmul(x, x), fmul(y, y)), fmul(z, z));
    const float cp = ffma(cz, z, ffma(cy, y, fmul(cx, x)));
    return fsub(fadd(c2, p2), fmul(2.0f, cp)) < r2;
}

__device__ __forceinline__ int cell_of(float x, float y, float z) {
    int ci = (int)(x * 10.0f); ci = ci < 0 ? 0 : (ci > 9 ? 9 : ci);
    int cj = (int)(y * 10.0f); cj = cj < 0 ? 0 : (cj > 9 ? 9 : cj);
    int ck = (int)(z * 10.0f); ck = ck < 0 ? 0 : (ck > 9 ? 9 : ck);
    return (ck * CELLS + cj) * CELLS + ci;   // x fastest -> x-ranges contiguous
}

// --- binning prep ----------------------------------------------------------
__global__ __launch_bounds__(256) void zero_kernel(int* __restrict__ hist) {
    const int t = blockIdx.x * 256 + threadIdx.x;
    if (t < B_SZ * NCELL) hist[t] = 0;
}

__global__ __launch_bounds__(256) void hist_kernel(
    const float* __restrict__ points, int* __restrict__ hist) {
    const int t = blockIdx.x * 256 + threadIdx.x;   // 0..32767
    const int b = t >> 14, n = t & (N_PTS - 1);
    const float x = points[(b * 3 + 0) * N_PTS + n];
    const float y = points[(b * 3 + 1) * N_PTS + n];
    const float z = points[(b * 3 + 2) * N_PTS + n];
    atomicAdd(&hist[b * NCELL + cell_of(x, y, z)], 1);
}

__global__ __launch_bounds__(1024) void scan_kernel(
    const int* __restrict__ hist, int* __restrict__ starts,
    int* __restrict__ cursor) {
    __shared__ int s[1024];
    const int t = threadIdx.x;
    for (int b = 0; b < B_SZ; ++b) {
        s[t] = (t < NCELL) ? hist[b * NCELL + t] : 0;
        __syncthreads();
        for (int off = 1; off < 1024; off <<= 1) {
            const int v = (t >= off) ? s[t - off] : 0;
            __syncthreads();
            s[t] += v;
            __syncthreads();
        }
        if (t < NCELL) {
            const int st = (t == 0) ? 0 : s[t - 1];
            starts[b * (NCELL + 1) + t] = st;
            cursor[b * NCELL + t] = st;
        }
        if (t == 0) starts[b * (NCELL + 1) + NCELL] = s[NCELL - 1];
        __syncthreads();
    }
}

__global__ __launch_bounds__(256) void scatter_kernel(
    const float* __restrict__ points, int* __restrict__ cursor,
    float4* __restrict__ binned) {
    const int t = blockIdx.x * 256 + threadIdx.x;   // 0..32767
    const int b = t >> 14, n = t & (N_PTS - 1);
    const float x = points[(b * 3 + 0) * N_PTS + n];
    const float y = points[(b * 3 + 1) * N_PTS + n];
    const float z = points[(b * 3 + 2) * N_PTS + n];
    const int pos = atomicAdd(&cursor[b * NCELL + cell_of(x, y, z)], 1);
    binned[b * N_PTS + pos] = make_float4(x, y, z, __int_as_float(n));
}

// ---------------------------------------------------------------------------
// Ball query, binned. One wave per center. Tests only the 27-cell
// neighborhood (~440 candidates vs ~7700 brute-force). A per-wave LDS bitmap
// over N restores exact index order: set bit n for each valid candidate,
// emit the first 32 set bits == "sort all valid indices, take first K".
// ---------------------------------------------------------------------------
__global__ __launch_bounds__(256) void ball_query_kernel(
    const float4* __restrict__ binned,   // (B,N) {x,y,z,idx}
    const float* __restrict__ centers,   // (B,3,M)
    const int* __restrict__ starts,      // (B,1001)
    int* __restrict__ idx_out)           // (B,K,M)
{
    const int lane = threadIdx.x & 63;
    const int wid  = threadIdx.x >> 6;
    const int cid  = blockIdx.x * 4 + wid;
    const int b = cid >> 12;
    const int m = cid & (M_CTR - 1);

    const float r2 = (float)(0.1 * 0.1);   // 0x3C23D70A

    const float cx = centers[(b * 3 + 0) * M_CTR + m];
    const float cy = centers[(b * 3 + 1) * M_CTR + m];
    const float cz = centers[(b * 3 + 2) * M_CTR + m];
    const float c2 = fadd(fadd(fmul(cx, cx), fmul(cy, cy)), fmul(cz, cz));

    __shared__ unsigned bitmap[4][N_PTS / 32];   // 2 KB per wave
    unsigned* bm = bitmap[wid];
#pragma unroll
    for (int j = 0; j < 8; ++j) bm[lane * 8 + j] = 0u;
    // wave-internal ordering: LDS pipe is in-order per wave; no barrier needed

    int ci = (int)(cx * 10.0f); ci = ci < 0 ? 0 : (ci > 9 ? 9 : ci);
    int cj = (int)(cy * 10.0f); cj = cj < 0 ? 0 : (cj > 9 ? 9 : cj);
    int ck = (int)(cz * 10.0f); ck = ck < 0 ? 0 : (ck > 9 ? 9 : ck);
    const int i0 = ci > 0 ? ci - 1 : 0;
    const int i1 = ci < 9 ? ci + 1 : 9;
    const int* st = starts + b * (NCELL + 1);
    const float4* __restrict__ bp = binned + b * N_PTS;

    for (int d = 0; d < 9; ++d) {
        const int jj = cj + (d % 3) - 1;
        const int kk = ck + (d / 3) - 1;
        if (jj < 0 || jj > 9 || kk < 0 || kk > 9) continue;
        const int base = (kk * CELLS + jj) * CELLS;
        const int lo = st[base + i0];
        const int hi = st[base + i1 + 1];
        for (int s0 = lo; s0 < hi; s0 += 64) {
            const int t = s0 + lane;
            if (t < hi) {
                const float4 p = bp[t];
                if (bq_valid(p.x, p.y, p.z, cx, cy, cz, c2, r2)) {
                    const int n = __float_as_int(p.w);
                    atomicOr((int*)&bm[n >> 5], 1 << (n & 31));
                }
            }
        }
    }

    // --- selection: first 32 set bits, in order ---
    unsigned w[8];
    int cnt = 0;
#pragma unroll
    for (int j = 0; j < 8; ++j) { w[j] = bm[lane * 8 + j]; cnt += __popc(w[j]); }

    // inclusive prefix over lanes
    int incl = cnt;
    for (int off = 1; off < 64; off <<= 1) {
        const int v = __shfl_up(incl, off);
        if (lane >= off) incl += v;
    }
    const int total = __shfl(incl, 63);
    int slot = incl - cnt;   // exclusive prefix

    // first set bit overall (pad value)
    int firstbit = 0x7fffffff;
#pragma unroll
    for (int j = 0; j < 8; ++j) {
        if (w[j] && firstbit == 0x7fffffff)
            firstbit = lane * 256 + j * 32 + (__ffs(w[j]) - 1);
    }
    for (int off = 32; off > 0; off >>= 1)
        firstbit = min(firstbit, __shfl_xor(firstbit, off));
    const int first_idx = (total == 0) ? 0 : firstbit;

    int* __restrict__ dst = idx_out + (b * K_NB) * M_CTR + m;
#pragma unroll
    for (int j = 0; j < 8; ++j) {
        unsigned x = w[j];
        while (x && slot < K_NB) {
            const int bit = __ffs(x) - 1;
            dst[slot * M_CTR] = lane * 256 + j * 32 + bit;
            x &= x - 1;
            ++slot;
        }
    }
    if (lane >= total && lane < K_NB) dst[lane * M_CTR] = first_idx;
}

// ---------------------------------------------------------------------------
// Kernel T: transpose points+feats -> pf (B,N,36) for contiguous gathers.
// ---------------------------------------------------------------------------
__global__ __launch_bounds__(256) void transpose_kernel(
    const float* __restrict__ points,   // (B,3,N)
    const float* __restrict__ feats,    // (B,C,N)
    float* __restrict__ pf)             // (B,N,36)
{
    __shared__ float tile[64][37];
    const int t  = threadIdx.x;
    const int b  = blockIdx.x >> 8;
    const int n0 = (blockIdx.x & 255) * 64;

    for (int i = t; i < NCH * 64; i += 256) {
        const int r = i >> 6;
        const int c = i & 63;
        float v;
        if (r < 3) v = points[(b * 3 + r) * N_PTS + n0 + c];
        else       v = feats[(b * C_FT + (r - 3)) * N_PTS + n0 + c];
        tile[c][r] = v;
    }
    if (t < 64) tile[t][35] = 0.0f;
    __syncthreads();

    float* __restrict__ dst = pf + ((size_t)b * N_PTS + n0) * 36;
    for (int o = t; o < 64 * 36; o += 256) {
        const int c = o / 36;
        const int r = o - c * 36;
        dst[o] = tile[c][r];
    }
}

// ---------------------------------------------------------------------------
// Kernel G: gather. Thread per (b,k,m): 9 contiguous float4 record reads,
// 35 m-coalesced plane stores.
// ---------------------------------------------------------------------------
__global__ __launch_bounds__(256) void gather_kernel(
    const float* __restrict__ pf,       // (B,N,36)
    const float* __restrict__ centers,  // (B,3,M)
    const int* __restrict__ idx,        // (B,K,M)
    float* __restrict__ out)            // (B,35,K,M)
{
    const int t = blockIdx.x * 256 + threadIdx.x;
    const int m = t & (M_CTR - 1);
    const int k = (t >> 12) & (K_NB - 1);
    const int b = t >> 17;

    const int n = idx[(b * K_NB + k) * M_CTR + m];
    const float4* __restrict__ src = (const float4*)(pf + ((size_t)b * N_PTS + n) * 36);

    float4 f[9];
#pragma unroll
    for (int i = 0; i < 9; ++i) f[i] = src[i];

    const float cx = centers[(b * 3 + 0) * M_CTR + m];
    const float cy = centers[(b * 3 + 1) * M_CTR + m];
    const float cz = centers[(b * 3 + 2) * M_CTR + m];

    float vv[36];
#pragma unroll
    for (int i = 0; i < 9; ++i) {
        vv[4 * i + 0] = f[i].x; vv[4 * i + 1] = f[i].y;
        vv[4 * i + 2] = f[i].z; vv[4 * i + 3] = f[i].w;
    }
    vv[0] -= cx; vv[1] -= cy; vv[2] -= cz;

    float* __restrict__ o = out + ((size_t)b * NCH * K_NB + k) * M_CTR + m;
#pragma unroll
    for (int ch = 0; ch < NCH; ++ch)
        o[(size_t)ch * CH_STRIDE] = vv[ch];
}

extern "C" void kernel_launch(void* const* d_in, const int* in_sizes, int n_in,
                              void* d_out, int out_size, void* d_ws, size_t ws_size,
                              hipStream_t stream) {
    const float* points  = (const float*)d_in[0];  // (2,3,16384)
    const float* centers = (const float*)d_in[1];  // (2,3,4096)
    const float* feats   = (const float*)d_in[2];  // (2,32,16384)
    float* out = (float*)d_out;                    // (2,35,32,4096)

    char* ws = (char*)d_ws;
    int*    idx    = (int*)ws;                               // 1 MiB
    float*  pf     = (float*)(ws + (1u << 20));              // 4.5 MiB
    int*    hist   = (int*)(ws + 5700 * 1024);               // 8 KB
    int*    cursor = (int*)(ws + 5716 * 1024);               // 8 KB
    int*    starts = (int*)(ws + 5732 * 1024);               // 8 KB
    float4* binned = (float4*)(ws + 5764 * 1024);            // 512 KB

    zero_kernel<<<(B_SZ * NCELL + 255) / 256, 256, 0, stream>>>(hist);
    hist_kernel<<<(B_SZ * N_PTS) / 256, 256, 0, stream>>>(points, hist);
    scan_kernel<<<1, 1024, 0, stream>>>(hist, starts, cursor);
    scatter_kernel<<<(B_SZ * N_PTS) / 256, 256, 0, stream>>>(points, cursor, binned);
    transpose_kernel<<<B_SZ * (N_PTS / 64), 256, 0, stream>>>(points, feats, pf);

    ball_query_kernel<<<(B_SZ * M_CTR) / 4, 256, 0, stream>>>(
        binned, centers, starts, idx);

    const int total = B_SZ * K_NB * M_CTR;
    gather_kernel<<<total / 256, 256, 0, stream>>>(pf, centers, idx, out);
}

// Round 9
// 108.593 us; speedup vs baseline: 1.6249x; 1.0548x over previous
//
#include <hip/hip_runtime.h>

#define B_SZ  2
#define N_PTS 16384
#define M_CTR 4096
#define C_FT  32
#define K_NB  32
#define NCH   35   // 3 + C_FT
#define CH_STRIDE (K_NB * M_CTR)   // 131072
#define CELLS 10
#define NCELL (CELLS * CELLS * CELLS)

// ---------------------------------------------------------------------------
// Exact single-rounded f32 ops, opaque to the compiler. v_fma_f32 ONLY where
// the numpy golden fuses (einsum cp accumulation). absmax==0.0 since R6 —
// DO NOT change the math.
// ---------------------------------------------------------------------------
__device__ __forceinline__ float fmul(float a, float b) {
    float r; asm("v_mul_f32 %0, %1, %2" : "=v"(r) : "v"(a), "v"(b)); return r;
}
__device__ __forceinline__ float fadd(float a, float b) {
    float r; asm("v_add_f32 %0, %1, %2" : "=v"(r) : "v"(a), "v"(b)); return r;
}
__device__ __forceinline__ float fsub(float a, float b) {
    float r; asm("v_sub_f32 %0, %1, %2" : "=v"(r) : "v"(a), "v"(b)); return r;
}
__device__ __forceinline__ float ffma(float a, float b, float c) {
    float r; asm("v_fma_f32 %0, %1, %2, %3" : "=v"(r) : "v"(a), "v"(b), "v"(c));
    return r;
}

__device__ __forceinline__ bool bq_valid(float x, float y, float z,
                                         float cx, float cy, float cz,
                                         float c2, float r2) {
    const float p2 = fadd(fadd(fmul(x, x), fmul(y, y)), fmul(z, z));
    const float cp = ffma(cz, z, ffma(cy, y, fmul(cx, x)));
    return fsub(fadd(c2, p2), fmul(2.0f, cp)) < r2;
}

__device__ __forceinline__ int cell_of(float x, float y, float z) {
    int ci = (int)(x * 10.0f); ci = ci < 0 ? 0 : (ci > 9 ? 9 : ci);
    int cj = (int)(y * 10.0f); cj = cj < 0 ? 0 : (cj > 9 ? 9 : cj);
    int ck = (int)(z * 10.0f); ck = ck < 0 ? 0 : (ck > 9 ? 9 : ck);
    return (ck * CELLS + cj) * CELLS + ci;   // x fastest
}

// --- hist (hist[] zeroed by hipMemsetAsync) --------------------------------
__global__ __launch_bounds__(256) void hist_kernel(
    const float* __restrict__ points, int* __restrict__ hist) {
    const int t = blockIdx.x * 256 + threadIdx.x;
    const int b = t >> 14, n = t & (N_PTS - 1);
    const float x = points[(b * 3 + 0) * N_PTS + n];
    const float y = points[(b * 3 + 1) * N_PTS + n];
    const float z = points[(b * 3 + 2) * N_PTS + n];
    atomicAdd(&hist[b * NCELL + cell_of(x, y, z)], 1);
}

// --- scan: one block per batch, 2 barriers (shuffle scan) ------------------
__global__ __launch_bounds__(1024) void scan_kernel(
    const int* __restrict__ hist, int* __restrict__ starts,
    int* __restrict__ cursor) {
    const int b = blockIdx.x;
    const int t = threadIdx.x;
    const int lane = t & 63, wid = t >> 6;
    __shared__ int wsum[16];
    const int v = (t < NCELL) ? hist[b * NCELL + t] : 0;
    int incl = v;
    for (int off = 1; off < 64; off <<= 1) {
        const int u = __shfl_up(incl, off);
        if (lane >= off) incl += u;
    }
    if (lane == 63) wsum[wid] = incl;
    __syncthreads();
    if (wid == 0 && lane < 16) {
        const int s = wsum[lane];
        int in2 = s;
        for (int off = 1; off < 16; off <<= 1) {
            const int u = __shfl_up(in2, off);
            if (lane >= off) in2 += u;
        }
        wsum[lane] = in2 - s;   // exclusive wave offset
    }
    __syncthreads();
    if (t < NCELL) {
        const int excl = incl - v + wsum[wid];
        starts[b * (NCELL + 1) + t] = excl;
        cursor[b * NCELL + t] = excl;
        if (t == NCELL - 1) starts[b * (NCELL + 1) + NCELL] = excl + v;
    }
}

// --- fused scatter (blocks 0..127) + transpose (blocks 128..639) -----------
__global__ __launch_bounds__(256) void scatter_transpose_kernel(
    const float* __restrict__ points, const float* __restrict__ feats,
    int* __restrict__ cursor, float4* __restrict__ binned,
    float* __restrict__ pf) {
    if (blockIdx.x < 128) {
        const int t = blockIdx.x * 256 + threadIdx.x;
        const int b = t >> 14, n = t & (N_PTS - 1);
        const float x = points[(b * 3 + 0) * N_PTS + n];
        const float y = points[(b * 3 + 1) * N_PTS + n];
        const float z = points[(b * 3 + 2) * N_PTS + n];
        const int pos = atomicAdd(&cursor[b * NCELL + cell_of(x, y, z)], 1);
        binned[b * N_PTS + pos] = make_float4(x, y, z, __int_as_float(n));
    } else {
        __shared__ float tile[64][37];
        const int bid = blockIdx.x - 128;
        const int t  = threadIdx.x;
        const int b  = bid >> 8;
        const int n0 = (bid & 255) * 64;
        for (int i = t; i < NCH * 64; i += 256) {
            const int r = i >> 6;
            const int c = i & 63;
            float v;
            if (r < 3) v = points[(b * 3 + r) * N_PTS + n0 + c];
            else       v = feats[(b * C_FT + (r - 3)) * N_PTS + n0 + c];
            tile[c][r] = v;
        }
        if (t < 64) tile[t][35] = 0.0f;
        __syncthreads();
        float* __restrict__ dst = pf + ((size_t)b * N_PTS + n0) * 36;
        for (int o = t; o < 64 * 36; o += 256) {
            const int c = o / 36;
            const int r = o - c * 36;
            dst[o] = tile[c][r];
        }
    }
}

// ---------------------------------------------------------------------------
// Ball query, binned. One wave per center; 27-cell neighborhood (~440
// candidates). Per-wave LDS bitmap over N restores exact index order.
// ---------------------------------------------------------------------------
__global__ __launch_bounds__(256) void ball_query_kernel(
    const float4* __restrict__ binned,   // (B,N) {x,y,z,idx}
    const float* __restrict__ centers,   // (B,3,M)
    const int* __restrict__ starts,      // (B,1001)
    int* __restrict__ idx_out)           // (B,K,M)
{
    const int lane = threadIdx.x & 63;
    const int wid  = threadIdx.x >> 6;
    const int cid  = blockIdx.x * 4 + wid;
    const int b = cid >> 12;
    const int m = cid & (M_CTR - 1);

    const float r2 = (float)(0.1 * 0.1);

    const float cx = centers[(b * 3 + 0) * M_CTR + m];
    const float cy = centers[(b * 3 + 1) * M_CTR + m];
    const float cz = centers[(b * 3 + 2) * M_CTR + m];
    const float c2 = fadd(fadd(fmul(cx, cx), fmul(cy, cy)), fmul(cz, cz));

    __shared__ unsigned bitmap[4][N_PTS / 32];   // 2 KB per wave
    unsigned* bm = bitmap[wid];
#pragma unroll
    for (int j = 0; j < 8; ++j) bm[lane * 8 + j] = 0u;

    int ci = (int)(cx * 10.0f); ci = ci < 0 ? 0 : (ci > 9 ? 9 : ci);
    int cj = (int)(cy * 10.0f); cj = cj < 0 ? 0 : (cj > 9 ? 9 : cj);
    int ck = (int)(cz * 10.0f); ck = ck < 0 ? 0 : (ck > 9 ? 9 : ck);
    const int i0 = ci > 0 ? ci - 1 : 0;
    const int i1 = ci < 9 ? ci + 1 : 9;
    const int* st = starts + b * (NCELL + 1);
    const float4* __restrict__ bp = binned + b * N_PTS;

    for (int d = 0; d < 9; ++d) {
        const int jj = cj + (d % 3) - 1;
        const int kk = ck + (d / 3) - 1;
        if (jj < 0 || jj > 9 || kk < 0 || kk > 9) continue;
        const int base = (kk * CELLS + jj) * CELLS;
        const int lo = st[base + i0];
        const int hi = st[base + i1 + 1];
        for (int s0 = lo; s0 < hi; s0 += 64) {
            const int t = s0 + lane;
            if (t < hi) {
                const float4 p = bp[t];
                if (bq_valid(p.x, p.y, p.z, cx, cy, cz, c2, r2)) {
                    const int n = __float_as_int(p.w);
                    atomicOr((int*)&bm[n >> 5], 1 << (n & 31));
                }
            }
        }
    }

    unsigned w[8];
    int cnt = 0;
#pragma unroll
    for (int j = 0; j < 8; ++j) { w[j] = bm[lane * 8 + j]; cnt += __popc(w[j]); }

    int incl = cnt;
    for (int off = 1; off < 64; off <<= 1) {
        const int v = __shfl_up(incl, off);
        if (lane >= off) incl += v;
    }
    const int total = __shfl(incl, 63);
    int slot = incl - cnt;

    int firstbit = 0x7fffffff;
#pragma unroll
    for (int j = 0; j < 8; ++j) {
        if (w[j] && firstbit == 0x7fffffff)
            firstbit = lane * 256 + j * 32 + (__ffs(w[j]) - 1);
    }
    for (int off = 32; off > 0; off >>= 1)
        firstbit = min(firstbit, __shfl_xor(firstbit, off));
    const int first_idx = (total == 0) ? 0 : firstbit;

    int* __restrict__ dst = idx_out + (b * K_NB) * M_CTR + m;
#pragma unroll
    for (int j = 0; j < 8; ++j) {
        unsigned x = w[j];
        while (x && slot < K_NB) {
            const int bit = __ffs(x) - 1;
            dst[slot * M_CTR] = lane * 256 + j * 32 + bit;
            x &= x - 1;
            ++slot;
        }
    }
    if (lane >= total && lane < K_NB) dst[lane * M_CTR] = first_idx;
}

// ---------------------------------------------------------------------------
// Gather: 2 consecutive-m elements per thread. Halves store instructions
// (float2 plane stores, 512 B/wave), halves idx loads, doubles load MLP.
// ---------------------------------------------------------------------------
__global__ __launch_bounds__(256) void gather_kernel(
    const float* __restrict__ pf,       // (B,N,36)
    const float* __restrict__ centers,  // (B,3,M)
    const int* __restrict__ idx,        // (B,K,M)
    float* __restrict__ out)            // (B,35,K,M)
{
    const int t = blockIdx.x * 256 + threadIdx.x;   // 0..131071
    const int m = (t & (M_CTR / 2 - 1)) * 2;
    const int k = (t >> 11) & (K_NB - 1);
    const int b = t >> 16;

    const int2 nn = *(const int2*)&idx[(b * K_NB + k) * M_CTR + m];
    const float4* __restrict__ s0 =
        (const float4*)(pf + ((size_t)b * N_PTS + nn.x) * 36);
    const float4* __restrict__ s1 =
        (const float4*)(pf + ((size_t)b * N_PTS + nn.y) * 36);

    float4 f0[9], f1[9];
#pragma unroll
    for (int i = 0; i < 9; ++i) { f0[i] = s0[i]; f1[i] = s1[i]; }

    const float2 cx = *(const float2*)&centers[(b * 3 + 0) * M_CTR + m];
    const float2 cy = *(const float2*)&centers[(b * 3 + 1) * M_CTR + m];
    const float2 cz = *(const float2*)&centers[(b * 3 + 2) * M_CTR + m];

    float v0[36], v1[36];
#pragma unroll
    for (int i = 0; i < 9; ++i) {
        v0[4 * i + 0] = f0[i].x; v0[4 * i + 1] = f0[i].y;
        v0[4 * i + 2] = f0[i].z; v0[4 * i + 3] = f0[i].w;
        v1[4 * i + 0] = f1[i].x; v1[4 * i + 1] = f1[i].y;
        v1[4 * i + 2] = f1[i].z; v1[4 * i + 3] = f1[i].w;
    }
    v0[0] -= cx.x; v0[1] -= cy.x; v0[2] -= cz.x;   // single f32 subtract
    v1[0] -= cx.y; v1[1] -= cy.y; v1[2] -= cz.y;

    float* __restrict__ o = out + ((size_t)b * NCH * K_NB + k) * M_CTR + m;
#pragma unroll
    for (int ch = 0; ch < NCH; ++ch)
        *(float2*)&o[(size_t)ch * CH_STRIDE] = make_float2(v0[ch], v1[ch]);
}

extern "C" void kernel_launch(void* const* d_in, const int* in_sizes, int n_in,
                              void* d_out, int out_size, void* d_ws, size_t ws_size,
                              hipStream_t stream) {
    const float* points  = (const float*)d_in[0];
    const float* centers = (const float*)d_in[1];
    const float* feats   = (const float*)d_in[2];
    float* out = (float*)d_out;

    char* ws = (char*)d_ws;
    int*    idx    = (int*)ws;                               // 1 MiB
    float*  pf     = (float*)(ws + (1u << 20));              // 4.5 MiB
    int*    hist   = (int*)(ws + 5700 * 1024);               // 8 KB
    int*    cursor = (int*)(ws + 5716 * 1024);               // 8 KB
    int*    starts = (int*)(ws + 5732 * 1024);               // 8 KB
    float4* binned = (float4*)(ws + 5764 * 1024);            // 512 KB

    hipMemsetAsync(hist, 0, B_SZ * NCELL * sizeof(int), stream);
    hist_kernel<<<(B_SZ * N_PTS) / 256, 256, 0, stream>>>(points, hist);
    scan_kernel<<<B_SZ, 1024, 0, stream>>>(hist, starts, cursor);
    scatter_transpose_kernel<<<128 + B_SZ * (N_PTS / 64), 256, 0, stream>>>(
        points, feats, cursor, binned, pf);
    ball_query_kernel<<<(B_SZ * M_CTR) / 4, 256, 0, stream>>>(
        binned, centers, starts, idx);
    gather_kernel<<<(B_SZ * K_NB * M_CTR / 2) / 256, 256, 0, stream>>>(
        pf, centers, idx, out);
}